// Round 1
// baseline (1640.235 us; speedup 1.0000x reference)
//
#include <hip/hip_runtime.h>

static constexpr int N = 100000;
static constexpr int E = 3200000;
static constexpr int NFEAT = 512;
static constexpr int K = 10;

// ---- workspace layout (bytes) ----
static constexpr size_t OFF_CNT    = 0;                              // N int
static constexpr size_t OFF_FILL   = 512ull * 1024;                  // N int
static constexpr size_t OFF_ROWPTR = 1024ull * 1024;                 // N+1 int
static constexpr size_t OFF_DINV   = 1536ull * 1024;                 // N float
static constexpr size_t OFF_BSUM   = 2048ull * 1024;                 // 128 int
static constexpr size_t OFF_EW     = 2560ull * 1024;                 // E int2 = 25.6 MB
static constexpr size_t OFF_HA     = OFF_EW + (size_t)E * 8 + 1024;  // N*64 f32
static constexpr size_t OFF_HB     = OFF_HA + (size_t)N * 64 * 4 + 1024;

// ---------- degree count ----------
__global__ __launch_bounds__(256) void count_k(const int* __restrict__ dst,
                                               int* __restrict__ cnt) {
  int e = blockIdx.x * 256 + threadIdx.x;
  if (e < E) atomicAdd(&cnt[dst[e]], 1);
}

__global__ __launch_bounds__(256) void dinv_k(const int* __restrict__ cnt,
                                              float* __restrict__ dinv) {
  int i = blockIdx.x * 256 + threadIdx.x;
  if (i < N) dinv[i] = 1.0f / sqrtf((float)(cnt[i] + 1));  // +1 self-loop
}

// ---------- exclusive scan (3 kernels) ----------
__device__ inline int wave_incl_scan(int x) {
  int lane = threadIdx.x & 63;
#pragma unroll
  for (int off = 1; off < 64; off <<= 1) {
    int y = __shfl_up(x, off, 64);
    if (lane >= off) x += y;
  }
  return x;
}

__global__ __launch_bounds__(256) void scan1_k(const int* __restrict__ cnt,
                                               int* __restrict__ rowptr,
                                               int* __restrict__ bsum) {
  __shared__ int wsum[4];
  int tid = threadIdx.x, wid = tid >> 6, lane = tid & 63;
  int base = blockIdx.x * 1024 + tid * 4;
  int4 v = {0, 0, 0, 0};
  if (base + 3 < N) {
    v = *(const int4*)(cnt + base);
  } else {
    if (base + 0 < N) v.x = cnt[base + 0];
    if (base + 1 < N) v.y = cnt[base + 1];
    if (base + 2 < N) v.z = cnt[base + 2];
    if (base + 3 < N) v.w = cnt[base + 3];
  }
  int tsum = v.x + v.y + v.z + v.w;
  int incl = wave_incl_scan(tsum);
  if (lane == 63) wsum[wid] = incl;
  __syncthreads();
  int wof = 0;
  for (int i = 0; i < wid; ++i) wof += wsum[i];
  int e0 = wof + incl - tsum;  // exclusive start for this thread
  if (base + 0 < N) rowptr[base + 0] = e0;
  if (base + 1 < N) rowptr[base + 1] = e0 + v.x;
  if (base + 2 < N) rowptr[base + 2] = e0 + v.x + v.y;
  if (base + 3 < N) rowptr[base + 3] = e0 + v.x + v.y + v.z;
  if (tid == 255) bsum[blockIdx.x] = wof + incl;  // block total
}

__global__ __launch_bounds__(128) void scan2_k(int* __restrict__ bsum) {
  __shared__ int w0sum;
  int tid = threadIdx.x, wid = tid >> 6, lane = tid & 63;
  int v = (tid < 98) ? bsum[tid] : 0;
  int incl = wave_incl_scan(v);
  if (wid == 0 && lane == 63) w0sum = incl;
  __syncthreads();
  int excl = incl - v + (wid ? w0sum : 0);
  if (tid < 98) bsum[tid] = excl;
}

__global__ __launch_bounds__(256) void scan3_k(int* __restrict__ rowptr,
                                               const int* __restrict__ bsum) {
  int i = blockIdx.x * 256 + threadIdx.x;
  if (i < N) rowptr[i] += bsum[blockIdx.x >> 2];
  if (i == 0) rowptr[N] = E;
}

// ---------- CSR fill ----------
__global__ __launch_bounds__(256) void fill_k(const int* __restrict__ src,
                                              const int* __restrict__ dst,
                                              const int* __restrict__ rowptr,
                                              int* __restrict__ fillc,
                                              const float* __restrict__ dinv,
                                              int2* __restrict__ ew) {
  int e = blockIdx.x * 256 + threadIdx.x;
  if (e >= E) return;
  int s = src[e], d = dst[e];
  int pos = rowptr[d] + atomicAdd(&fillc[d], 1);
  float w = dinv[s] * dinv[d];
  ew[pos] = make_int2(s, __float_as_int(w));
}

// ---------- GEMM1: h1 = relu(x @ W1 + b1), [N,512]x[512,64] ----------
__global__ __launch_bounds__(256) void gemm1_k(const float* __restrict__ x,
                                               const float* __restrict__ W1,
                                               const float* __restrict__ b1,
                                               float* __restrict__ h1) {
  __shared__ float xs[16][256];   // transposed x tile: xs[k][node]
  __shared__ float w1s[16 * 64];  // W1 tile
  const int tid = threadIdx.x;
  const int n0 = blockIdx.x * 256;
  const int tn = tid & 127;  // node pair: tn, tn+128
  const int jh = tid >> 7;   // j half: [jh*32, jh*32+32)
  float4 acca[8], accb[8];
#pragma unroll
  for (int i = 0; i < 8; ++i) {
    acca[i] = float4{0.f, 0.f, 0.f, 0.f};
    accb[i] = float4{0.f, 0.f, 0.f, 0.f};
  }
  const int rowA = min(n0 + tid, N - 1);
  const float* xr = x + (size_t)rowA * NFEAT;
  for (int k0 = 0; k0 < NFEAT; k0 += 16) {
    float4 a0 = *(const float4*)(xr + k0 + 0);
    float4 a1 = *(const float4*)(xr + k0 + 4);
    float4 a2 = *(const float4*)(xr + k0 + 8);
    float4 a3 = *(const float4*)(xr + k0 + 12);
    float4 wv = *(const float4*)(W1 + (size_t)k0 * 64 + tid * 4);
    __syncthreads();  // previous iteration's reads complete
    xs[0][tid] = a0.x;  xs[1][tid] = a0.y;  xs[2][tid] = a0.z;  xs[3][tid] = a0.w;
    xs[4][tid] = a1.x;  xs[5][tid] = a1.y;  xs[6][tid] = a1.z;  xs[7][tid] = a1.w;
    xs[8][tid] = a2.x;  xs[9][tid] = a2.y;  xs[10][tid] = a2.z; xs[11][tid] = a2.w;
    xs[12][tid] = a3.x; xs[13][tid] = a3.y; xs[14][tid] = a3.z; xs[15][tid] = a3.w;
    *(float4*)&w1s[tid * 4] = wv;
    __syncthreads();
#pragma unroll
    for (int kk = 0; kk < 16; ++kk) {
      float xa = xs[kk][tn];
      float xb = xs[kk][tn + 128];
      const float* wr = &w1s[kk * 64 + jh * 32];
#pragma unroll
      for (int jj = 0; jj < 8; ++jj) {
        float4 w4 = *(const float4*)(wr + jj * 4);
        acca[jj].x += xa * w4.x; acca[jj].y += xa * w4.y;
        acca[jj].z += xa * w4.z; acca[jj].w += xa * w4.w;
        accb[jj].x += xb * w4.x; accb[jj].y += xb * w4.y;
        accb[jj].z += xb * w4.z; accb[jj].w += xb * w4.w;
      }
    }
  }
  const int na = n0 + tn, nb = na + 128;
#pragma unroll
  for (int jj = 0; jj < 8; ++jj) {
    int j = jh * 32 + jj * 4;
    float4 bb = *(const float4*)(b1 + j);
    float4 ra, rb;
    ra.x = fmaxf(acca[jj].x + bb.x, 0.f); ra.y = fmaxf(acca[jj].y + bb.y, 0.f);
    ra.z = fmaxf(acca[jj].z + bb.z, 0.f); ra.w = fmaxf(acca[jj].w + bb.w, 0.f);
    rb.x = fmaxf(accb[jj].x + bb.x, 0.f); rb.y = fmaxf(accb[jj].y + bb.y, 0.f);
    rb.z = fmaxf(accb[jj].z + bb.z, 0.f); rb.w = fmaxf(accb[jj].w + bb.w, 0.f);
    if (na < N) *(float4*)(h1 + (size_t)na * 64 + j) = ra;
    if (nb < N) *(float4*)(h1 + (size_t)nb * 64 + j) = rb;
  }
}

// ---------- GEMM2: h0 = h1 @ W2 + b2 ; out = temp[0]*h0 ----------
__global__ __launch_bounds__(256) void gemm2_k(const float* __restrict__ h1,
                                               const float* __restrict__ W2,
                                               const float* __restrict__ b2,
                                               const float* __restrict__ temp,
                                               float* __restrict__ h0,
                                               float* __restrict__ out) {
  __shared__ float w2s[64 * 64];
  const int tid = threadIdx.x;
#pragma unroll
  for (int i = 0; i < 4; ++i)
    *(float4*)&w2s[(i * 256 + tid) * 4] = *(const float4*)(W2 + (size_t)(i * 256 + tid) * 4);
  __syncthreads();
  const int node = blockIdx.x * 256 + tid;
  if (node >= N) return;
  float4 acc[16];
#pragma unroll
  for (int c = 0; c < 16; ++c) acc[c] = *(const float4*)(b2 + c * 4);
  const float* hr = h1 + (size_t)node * 64;
  for (int j0 = 0; j0 < 64; j0 += 4) {
    float4 hv = *(const float4*)(hr + j0);
    float hv4[4] = {hv.x, hv.y, hv.z, hv.w};
#pragma unroll
    for (int l = 0; l < 4; ++l) {
      const float* wr = &w2s[(j0 + l) * 64];
#pragma unroll
      for (int c = 0; c < 16; ++c) {
        float4 w4 = *(const float4*)(wr + c * 4);
        acc[c].x += hv4[l] * w4.x; acc[c].y += hv4[l] * w4.y;
        acc[c].z += hv4[l] * w4.z; acc[c].w += hv4[l] * w4.w;
      }
    }
  }
  float t0 = temp[0];
  float* hp = h0 + (size_t)node * 64;
  float* op = out + (size_t)node * 64;
#pragma unroll
  for (int c = 0; c < 16; ++c) {
    *(float4*)(hp + c * 4) = acc[c];
    float4 o;
    o.x = t0 * acc[c].x; o.y = t0 * acc[c].y;
    o.z = t0 * acc[c].z; o.w = t0 * acc[c].w;
    *(float4*)(op + c * 4) = o;
  }
}

// ---------- propagation: hout = A_hat @ hin ; out += temp[kp1]*hout ----------
__global__ __launch_bounds__(256) void prop_k(const float* __restrict__ hin,
                                              float* __restrict__ hout,
                                              float* __restrict__ out,
                                              const int* __restrict__ rowptr,
                                              const int2* __restrict__ ew,
                                              const float* __restrict__ dinv,
                                              const float* __restrict__ temp,
                                              int kp1) {
  const int lane = threadIdx.x & 63;
  const int node = blockIdx.x * 4 + (threadIdx.x >> 6);  // N%4==0, grid exact
  const int rs = __builtin_amdgcn_readfirstlane(rowptr[node]);
  const int re = __builtin_amdgcn_readfirstlane(rowptr[node + 1]);
  const float di = dinv[node];
  const int base = node * 64 + lane;
  float acc0 = di * di * hin[base];  // self-loop term
  float acc1 = 0.f, acc2 = 0.f, acc3 = 0.f;
  int e = rs;
  for (; e + 4 <= re; e += 4) {
    int2 p0 = ew[e], p1 = ew[e + 1], p2 = ew[e + 2], p3 = ew[e + 3];
    acc0 += __int_as_float(p0.y) * hin[p0.x * 64 + lane];
    acc1 += __int_as_float(p1.y) * hin[p1.x * 64 + lane];
    acc2 += __int_as_float(p2.y) * hin[p2.x * 64 + lane];
    acc3 += __int_as_float(p3.y) * hin[p3.x * 64 + lane];
  }
  for (; e < re; ++e) {
    int2 p = ew[e];
    acc0 += __int_as_float(p.y) * hin[p.x * 64 + lane];
  }
  float acc = (acc0 + acc1) + (acc2 + acc3);
  hout[base] = acc;
  out[base] += temp[kp1] * acc;
}

extern "C" void kernel_launch(void* const* d_in, const int* in_sizes, int n_in,
                              void* d_out, int out_size, void* d_ws, size_t ws_size,
                              hipStream_t stream) {
  const float* x = (const float*)d_in[0];
  const int* ei = (const int*)d_in[1];
  const float* W1 = (const float*)d_in[2];
  const float* b1 = (const float*)d_in[3];
  const float* W2 = (const float*)d_in[4];
  const float* b2 = (const float*)d_in[5];
  const float* temp = (const float*)d_in[6];
  const int* srcp = ei;       // edge_index[0]
  const int* dstp = ei + E;   // edge_index[1]

  unsigned char* ws = (unsigned char*)d_ws;
  int* cnt = (int*)(ws + OFF_CNT);
  int* fillc = (int*)(ws + OFF_FILL);
  int* rowptr = (int*)(ws + OFF_ROWPTR);
  float* dinv = (float*)(ws + OFF_DINV);
  int* bsum = (int*)(ws + OFF_BSUM);
  int2* ew = (int2*)(ws + OFF_EW);
  float* hA = (float*)(ws + OFF_HA);
  float* hB = (float*)(ws + OFF_HB);
  float* out = (float*)d_out;

  hipMemsetAsync(cnt, 0, (size_t)N * 4, stream);
  hipMemsetAsync(fillc, 0, (size_t)N * 4, stream);

  count_k<<<E / 256, 256, 0, stream>>>(dstp, cnt);
  dinv_k<<<(N + 255) / 256, 256, 0, stream>>>(cnt, dinv);
  scan1_k<<<(N + 1023) / 1024, 256, 0, stream>>>(cnt, rowptr, bsum);
  scan2_k<<<1, 128, 0, stream>>>(bsum);
  scan3_k<<<(N + 255) / 256, 256, 0, stream>>>(rowptr, bsum);
  fill_k<<<E / 256, 256, 0, stream>>>(srcp, dstp, rowptr, fillc, dinv, ew);

  gemm1_k<<<(N + 255) / 256, 256, 0, stream>>>(x, W1, b1, hB);
  gemm2_k<<<(N + 255) / 256, 256, 0, stream>>>(hB, W2, b2, temp, hA, out);

  const float* hin = hA;
  float* hout = hB;
  for (int k = 0; k < K; ++k) {
    prop_k<<<N / 4, 256, 0, stream>>>(hin, hout, out, rowptr, ew, dinv, temp, k + 1);
    float* t = (float*)hin;
    hin = hout;
    hout = t;
  }
}